// Round 4
// baseline (791.317 us; speedup 1.0000x reference)
//
#include <hip/hip_runtime.h>
#include <hip/hip_bf16.h>

// x: (2,3,512,512) fp32 -> conv1 s2 p1 -> h: chunked layout [b][4][256][256][16]
//   (64B per pixel-chunk => coalesced full-line reads for conv taps & gathers)
// off conv: 3x3 p1, 64->20 (both branches fused), raw outputs (2,65536,10)
// GN stats -> k_dsc applies GN+tanh inline, 2-pt lerp sample + K=5 conv -> cat (2,65536,16)
// final: GN + 1x1 conv 16->64 + BN + ReLU -> fp32 NCHW (2,64,256,256)

#define EPSF 1e-5f

typedef __attribute__((ext_vector_type(4))) float f4;

// h element index: ((b*4 + chunk)*65536 + i*256 + j)*16 + c   (c in 0..15)

// ---------------- Kernel 1: conv1 + bn1 + relu -> h chunked ------------------
// block = 256 (4 waves); wave wid = channel-chunk wid (oc 16wid..16wid+15);
// lanes = 64 j-pixels; 2 rows/thread. grid = 1024.
__global__ __launch_bounds__(256) void k_conv1(
    const float* __restrict__ x, const float* __restrict__ w,
    const float* __restrict__ g, const float* __restrict__ bb,
    const float* __restrict__ m, const float* __restrict__ v,
    float* __restrict__ h)
{
    __shared__ float wl[27 * 64];            // [tap][oc]
    __shared__ float scale[64], shift[64];
    int t = threadIdx.x;
    for (int idx = t; idx < 1728; idx += 256) {
        int tap = idx >> 6, oc = idx & 63;
        wl[idx] = w[oc * 27 + tap];
    }
    if (t < 64) {
        float sc = g[t] * rsqrtf(v[t] + EPSF);
        scale[t] = sc; shift[t] = bb[t] - m[t] * sc;
    }
    __syncthreads();
    int lane = t & 63, wid = t >> 6;
    int blk = blockIdx.x;
    int b = blk >> 9;
    int rem = blk & 511;
    int i0 = (rem >> 2) * 2;
    int j0 = (rem & 3) * 64;
    int j = j0 + lane;
    f4 acc[2][4];
    #pragma unroll
    for (int r = 0; r < 2; ++r)
        #pragma unroll
        for (int q = 0; q < 4; ++q) acc[r][q] = (f4)0.f;
    #pragma unroll
    for (int ic = 0; ic < 3; ++ic) {
        #pragma unroll
        for (int dy = 0; dy < 3; ++dy) {
            const float* rowp[2]; bool vy[2];
            #pragma unroll
            for (int r = 0; r < 2; ++r) {
                int y = 2 * (i0 + r) + dy - 1;
                vy[r] = (unsigned)y < 512u;
                rowp[r] = x + ((size_t)(b * 3 + ic) * 512 + (vy[r] ? y : 0)) * 512;
            }
            #pragma unroll
            for (int dx = 0; dx < 3; ++dx) {
                int xx = 2 * j + dx - 1;
                bool vx = (unsigned)xx < 512u;
                int tap = ic * 9 + dy * 3 + dx;
                f4 w4[4];
                #pragma unroll
                for (int q = 0; q < 4; ++q)
                    w4[q] = *(const f4*)&wl[tap * 64 + wid * 16 + q * 4];
                #pragma unroll
                for (int r = 0; r < 2; ++r) {
                    float xv = (vy[r] && vx) ? rowp[r][xx] : 0.f;
                    #pragma unroll
                    for (int q = 0; q < 4; ++q) acc[r][q] += xv * w4[q];
                }
            }
        }
    }
    #pragma unroll
    for (int r = 0; r < 2; ++r) {
        size_t ij = (size_t)(i0 + r) * 256 + j;
        float* hp = h + ((size_t)(b * 4 + wid) * 65536 + ij) * 16;
        #pragma unroll
        for (int q = 0; q < 4; ++q) {
            f4 sc = *(const f4*)&scale[wid * 16 + q * 4];
            f4 sh = *(const f4*)&shift[wid * 16 + q * 4];
            f4 val = acc[r][q] * sc + sh;
            f4 rv;
            #pragma unroll
            for (int e = 0; e < 4; ++e) rv[e] = fmaxf(val[e], 0.f);
            *(f4*)(hp + q * 4) = rv;
        }
    }
}

// ---------------- Kernel 2: both offset convs (3x3 p1, 64 -> 20) -------------
// block = 256; tile 64 j (lanes) x 8 i (4 waves x 2 rows/thread). grid = 256.
__global__ __launch_bounds__(256) void k_offconv(
    const float* __restrict__ h,
    const float* __restrict__ wx, const float* __restrict__ wy,
    const float* __restrict__ bx, const float* __restrict__ by,
    float* __restrict__ offx, float* __restrict__ offy)
{
    __shared__ float wl[9 * 64 * 20];        // [tap][c][o20], 80B rows
    __shared__ float bias[20];
    int t = threadIdx.x;
    for (int idx = t; idx < 11520; idx += 256) {
        int o = idx % 20;
        int rest = idx / 20;                 // tap*64 + c
        int c = rest & 63, tap = rest >> 6;
        wl[idx] = (o < 10) ? wx[((size_t)o * 64 + c) * 9 + tap]
                           : wy[((size_t)(o - 10) * 64 + c) * 9 + tap];
    }
    if (t < 20) bias[t] = (t < 10) ? bx[t] : by[t - 10];
    __syncthreads();
    int lane = t & 63, wid = t >> 6;
    int blk = blockIdx.x;
    int b = blk >> 7;
    int rem = blk & 127;
    int i0 = (rem >> 2) * 8 + wid * 2;
    int j0 = (rem & 3) * 64;
    int j = j0 + lane;
    f4 acc[2][5];
    #pragma unroll
    for (int r = 0; r < 2; ++r)
        #pragma unroll
        for (int q = 0; q < 5; ++q) acc[r][q] = (f4)0.f;
    #pragma unroll 1
    for (int chunk = 0; chunk < 4; ++chunk) {
        const float* hc = h + ((size_t)(b * 4 + chunk) * 65536) * 16;
        #pragma unroll 1
        for (int ky = 0; ky < 3; ++ky) {
            int y0 = i0 + ky - 1;
            int y1 = y0 + 1;
            bool vy0 = (unsigned)y0 < 256u;
            bool vy1 = (unsigned)y1 < 256u;
            #pragma unroll
            for (int kx = 0; kx < 3; ++kx) {
                int xx = j + kx - 1;
                bool vx = (unsigned)xx < 256u;
                int xc = vx ? xx : 0;
                const float* p0 = hc + ((size_t)(vy0 ? y0 : 0) * 256 + xc) * 16;
                const float* p1 = hc + ((size_t)(vy1 ? y1 : 0) * 256 + xc) * 16;
                f4 hv[2][4];
                #pragma unroll
                for (int cq = 0; cq < 4; ++cq) {
                    hv[0][cq] = (vy0 && vx) ? *(const f4*)(p0 + cq * 4) : (f4)0.f;
                    hv[1][cq] = (vy1 && vx) ? *(const f4*)(p1 + cq * 4) : (f4)0.f;
                }
                const float* wt = &wl[((ky * 3 + kx) * 64 + chunk * 16) * 20];
                #pragma unroll
                for (int cq = 0; cq < 4; ++cq)
                    #pragma unroll
                    for (int ci = 0; ci < 4; ++ci) {
                        const float* wr = &wt[(cq * 4 + ci) * 20];
                        f4 w0 = *(const f4*)&wr[0];
                        f4 w1 = *(const f4*)&wr[4];
                        f4 w2 = *(const f4*)&wr[8];
                        f4 w3 = *(const f4*)&wr[12];
                        f4 w4v = *(const f4*)&wr[16];
                        #pragma unroll
                        for (int r = 0; r < 2; ++r) {
                            float hvv = hv[r][cq][ci];
                            acc[r][0] += hvv * w0;
                            acc[r][1] += hvv * w1;
                            acc[r][2] += hvv * w2;
                            acc[r][3] += hvv * w3;
                            acc[r][4] += hvv * w4v;
                        }
                    }
            }
        }
    }
    #pragma unroll
    for (int r = 0; r < 2; ++r) {
        size_t p = (size_t)b * 65536 + (size_t)(i0 + r) * 256 + j;
        float* ox = offx + p * 10;
        float* oy = offy + p * 10;
        #pragma unroll
        for (int q = 0; q < 5; ++q)
            #pragma unroll
            for (int e = 0; e < 4; ++e) {
                int o = q * 4 + e;
                float val = acc[r][q][e] + bias[o];
                if (o < 10) ox[o] = val; else oy[o - 10] = val;
            }
    }
}

// ---------------- block reduce helper ----------------------------------------
__device__ __forceinline__ void block_reduce2(float& s, float& s2, float* lds) {
    #pragma unroll
    for (int o = 32; o >= 1; o >>= 1) {
        s  += __shfl_xor(s,  o, 64);
        s2 += __shfl_xor(s2, o, 64);
    }
    int wv = threadIdx.x >> 6, lane = threadIdx.x & 63;
    if (lane == 0) { lds[wv * 2] = s; lds[wv * 2 + 1] = s2; }
    __syncthreads();
    if (threadIdx.x == 0) {
        int nw = blockDim.x >> 6;
        float a = 0.f, b2 = 0.f;
        for (int k = 0; k < nw; ++k) { a += lds[k * 2]; b2 += lds[k * 2 + 1]; }
        s = a; s2 = b2;
    }
}

// ---------------- Kernel 3: offset GN stats ----------------------------------
__global__ __launch_bounds__(1024) void k_offstats(
    const float* __restrict__ offx,
    const float* __restrict__ offy,
    float* __restrict__ stats)               // 20 * {mean, rstd}
{
    __shared__ float lds[32];
    int gid = blockIdx.x;                    // branch*10 + b*5 + g
    int branch = gid / 10;
    int b = (gid / 5) % 2;
    int g = gid % 5;
    const float* arr = branch ? offy : offx;
    int t = threadIdx.x;
    float s = 0.f, s2 = 0.f;
    for (int pix = t; pix < 65536; pix += 1024) {
        const float* pp = &arr[((size_t)b * 65536 + pix) * 10 + g * 2];
        float a = pp[0], c = pp[1];
        s += a + c; s2 += a * a + c * c;
    }
    block_reduce2(s, s2, lds);
    if (t == 0) {
        float n = 131072.f;
        float mean = s / n;
        float var = s2 / n - mean * mean;
        stats[gid * 2] = mean;
        stats[gid * 2 + 1] = rsqrtf(var + EPSF);
    }
}

// ---------------- Kernel 4: GN+tanh (inline) + 2pt-lerp + deform conv ---------
// block = 256; tile 64 j (lanes) x 16 i (4 waves x 4 rows/thread). grid (128,2).
__global__ __launch_bounds__(256) void k_dsc(
    const float* __restrict__ h,
    const float* __restrict__ offx, const float* __restrict__ offy,
    const float* __restrict__ stats,
    const float* __restrict__ gx, const float* __restrict__ bxg,
    const float* __restrict__ gy, const float* __restrict__ byg,
    const float* __restrict__ wx_,  // dscx_w (8,64,5)
    const float* __restrict__ wy_,  // dscy_w (8,64,5)
    const float* __restrict__ bx_, const float* __restrict__ by_,
    float* __restrict__ cat)        // (2,65536,16)
{
    int branch = blockIdx.y;
    __shared__ float wl[2560];               // [k][c][oc8], 32B rows
    __shared__ float bias[8];
    const float* wsrc = branch ? wy_ : wx_;
    int t = threadIdx.x;
    for (int idx = t; idx < 2560; idx += 256) {
        int oc = idx & 7;
        int rest = idx >> 3;                 // k*64 + c
        int c = rest & 63, k = rest >> 6;
        wl[idx] = wsrc[(size_t)oc * 320 + c * 5 + k];
    }
    if (t < 8) bias[t] = (branch ? by_ : bx_)[t];
    __syncthreads();
    int lane = t & 63, wid = t >> 6;
    int blk = blockIdx.x;
    int b = blk >> 6;
    int rem = blk & 63;
    int i0 = (rem >> 2) * 16 + wid * 4;
    int j0 = (rem & 3) * 64;
    int j = j0 + lane;
    const float* offarr = branch ? offy : offx;
    const float* goff = branch ? gy : gx;
    const float* boff = branch ? byg : bxg;
    int cbase = branch * 5;
    int sbase = branch * 10 + b * 5;
    float cum[4][5];
    #pragma unroll
    for (int r = 0; r < 4; ++r) {
        size_t p = (size_t)b * 65536 + (size_t)(i0 + r) * 256 + j;
        const float* op = offarr + p * 10 + cbase;
        float tv[4];
        const int idxs[4] = {0, 1, 3, 4};
        #pragma unroll
        for (int u = 0; u < 4; ++u) {
            int c = cbase + idxs[u];
            int g = c >> 1;
            int sidx = sbase + (g - branch * 5) + branch * 5;  // = branch*10 + b*5 + g
            // note: sbase already = branch*10 + b*5, so sidx = branch*10+b*5+g:
            sidx = branch * 10 + b * 5 + g;
            float mean = stats[sidx * 2], rstd = stats[sidx * 2 + 1];
            float val = (op[idxs[u]] - mean) * rstd * goff[c] + boff[c];
            tv[u] = tanhf(val);
        }
        cum[r][0] = tv[0] + tv[1]; cum[r][1] = tv[1]; cum[r][2] = 0.f;
        cum[r][3] = tv[2]; cum[r][4] = tv[2] + tv[3];
    }
    f4 acc[4][2];
    #pragma unroll
    for (int r = 0; r < 4; ++r) { acc[r][0] = (f4)0.f; acc[r][1] = (f4)0.f; }
    #pragma unroll
    for (int k = 0; k < 5; ++k) {
        int pixA[4], pixB[4]; float fr[4];
        #pragma unroll
        for (int r = 0; r < 4; ++r) {
            int i = i0 + r;
            if (branch == 0) {
                float yf = (float)i + cum[r][k];
                yf = fminf(fmaxf(yf, 0.f), 255.f);
                float y0 = floorf(yf);
                fr[r] = yf - y0;
                int y0i = (int)y0;
                int y1i = min(y0i + 1, 255);
                int xi = min(max(j + k - 2, 0), 255);
                pixA[r] = y0i * 256 + xi;
                pixB[r] = y1i * 256 + xi;
            } else {
                float xf = (float)j + cum[r][k];
                xf = fminf(fmaxf(xf, 0.f), 255.f);
                float x0 = floorf(xf);
                fr[r] = xf - x0;
                int x0i = (int)x0;
                int x1i = min(x0i + 1, 255);
                int yi = min(max(i + k - 2, 0), 255);
                pixA[r] = yi * 256 + x0i;
                pixB[r] = yi * 256 + x1i;
            }
        }
        #pragma unroll 1
        for (int chunk = 0; chunk < 4; ++chunk) {
            const float* hc = h + ((size_t)(b * 4 + chunk) * 65536) * 16;
            const float* wk = &wl[((size_t)k * 64 + chunk * 16) * 8];
            #pragma unroll
            for (int cq = 0; cq < 4; ++cq) {
                f4 vv[4];
                #pragma unroll
                for (int r = 0; r < 4; ++r) {
                    f4 va = *(const f4*)(hc + (size_t)pixA[r] * 16 + cq * 4);
                    f4 vb = *(const f4*)(hc + (size_t)pixB[r] * 16 + cq * 4);
                    vv[r] = va + fr[r] * (vb - va);
                }
                #pragma unroll
                for (int ci = 0; ci < 4; ++ci) {
                    f4 w0 = *(const f4*)&wk[(cq * 4 + ci) * 8];
                    f4 w1 = *(const f4*)&wk[(cq * 4 + ci) * 8 + 4];
                    #pragma unroll
                    for (int r = 0; r < 4; ++r) {
                        acc[r][0] += vv[r][ci] * w0;
                        acc[r][1] += vv[r][ci] * w1;
                    }
                }
            }
        }
    }
    #pragma unroll
    for (int r = 0; r < 4; ++r) {
        size_t p = (size_t)b * 65536 + (size_t)(i0 + r) * 256 + j;
        f4 v0 = acc[r][0] + *(const f4*)&bias[0];
        f4 v1 = acc[r][1] + *(const f4*)&bias[4];
        *(f4*)&cat[p * 16 + branch * 8] = v0;
        *(f4*)&cat[p * 16 + branch * 8 + 4] = v1;
    }
}

// ---------------- Kernel 5: cat GN stats (8 groups of 4ch x 65536) ------------
__global__ __launch_bounds__(1024) void k_catstats(
    const float* __restrict__ cat, float* __restrict__ stats)
{
    __shared__ float lds[32];
    int gid = blockIdx.x;                    // b*4 + branch*2 + g
    int b = gid >> 2;
    int cbase = ((gid >> 1) & 1) * 8 + (gid & 1) * 4;
    int t = threadIdx.x;
    float s = 0.f, s2 = 0.f;
    for (int pix = t; pix < 65536; pix += 1024) {
        const float* pp = &cat[((size_t)b * 65536 + pix) * 16 + cbase];
        #pragma unroll
        for (int c = 0; c < 4; ++c) { float a = pp[c]; s += a; s2 += a * a; }
    }
    block_reduce2(s, s2, lds);
    if (t == 0) {
        float n = 262144.f;
        float mean = s / n;
        float var = s2 / n - mean * mean;
        stats[gid * 2] = mean;
        stats[gid * 2 + 1] = rsqrtf(var + EPSF);
    }
}

// ---------------- Kernel 6: GN+relu + 1x1 conv + bn2 + relu -> fp32 out -------
__global__ __launch_bounds__(256) void k_final(
    const float* __restrict__ cat,
    const float* __restrict__ stats,
    const float* __restrict__ gnx_g, const float* __restrict__ gnx_b,
    const float* __restrict__ gny_g, const float* __restrict__ gny_b,
    const float* __restrict__ w2,    // (64,16)
    const float* __restrict__ g2, const float* __restrict__ b2,
    const float* __restrict__ m2, const float* __restrict__ v2,
    float* __restrict__ out)         // (2,64,256,256)
{
    __shared__ float wl[1024];
    __shared__ float sc2[64], sh2[64];
    __shared__ float cmean[16], crstd[16], cg[16], cb[16];
    int t = threadIdx.x;
    int pbase = blockIdx.x * 64;
    int b = pbase >> 16;
    for (int idx = t; idx < 1024; idx += 256) wl[idx] = w2[idx];
    if (t < 64) {
        float sc = g2[t] * rsqrtf(v2[t] + EPSF);
        sc2[t] = sc;
        sh2[t] = b2[t] - m2[t] * sc;
    }
    if (t < 16) {
        int branch = t >> 3; int cc = t & 7; int g = cc >> 2;
        int sidx = b * 4 + branch * 2 + g;
        cmean[t] = stats[sidx * 2];
        crstd[t] = stats[sidx * 2 + 1];
        cg[t] = branch ? gny_g[cc] : gnx_g[cc];
        cb[t] = branch ? gny_b[cc] : gnx_b[cc];
    }
    __syncthreads();
    int lane = t & 63, wq = t >> 6;
    int p = pbase + lane;
    int ij = p & 65535;
    float vv[16];
    const float* cp = &cat[(size_t)p * 16];
    #pragma unroll
    for (int c = 0; c < 16; ++c) {
        float x = (cp[c] - cmean[c]) * crstd[c] * cg[c] + cb[c];
        vv[c] = fmaxf(x, 0.f);
    }
    #pragma unroll
    for (int q = 0; q < 16; ++q) {
        int oc = wq + q * 4;
        float s = 0.f;
        #pragma unroll
        for (int c = 0; c < 16; ++c) s += vv[c] * wl[oc * 16 + c];
        float r = fmaxf(s * sc2[oc] + sh2[oc], 0.f);
        out[((size_t)(b * 64 + oc) << 16) + ij] = r;
    }
}

extern "C" void kernel_launch(void* const* d_in, const int* in_sizes, int n_in,
                              void* d_out, int out_size, void* d_ws, size_t ws_size,
                              hipStream_t stream) {
    const float* x       = (const float*)d_in[0];
    const float* conv1_w = (const float*)d_in[1];
    const float* bn1_g   = (const float*)d_in[2];
    const float* bn1_b   = (const float*)d_in[3];
    const float* bn1_m   = (const float*)d_in[4];
    const float* bn1_v   = (const float*)d_in[5];
    const float* offx_w  = (const float*)d_in[6];
    const float* offx_b  = (const float*)d_in[7];
    const float* gnoffx_g= (const float*)d_in[8];
    const float* gnoffx_b= (const float*)d_in[9];
    const float* dscx_w  = (const float*)d_in[10];
    const float* dscx_b  = (const float*)d_in[11];
    const float* gnx_g   = (const float*)d_in[12];
    const float* gnx_b   = (const float*)d_in[13];
    const float* offy_w  = (const float*)d_in[14];
    const float* offy_b  = (const float*)d_in[15];
    const float* gnoffy_g= (const float*)d_in[16];
    const float* gnoffy_b= (const float*)d_in[17];
    const float* dscy_w  = (const float*)d_in[18];
    const float* dscy_b  = (const float*)d_in[19];
    const float* gny_g   = (const float*)d_in[20];
    const float* gny_b   = (const float*)d_in[21];
    const float* conv2_w = (const float*)d_in[22];
    const float* bn2_g   = (const float*)d_in[23];
    const float* bn2_b   = (const float*)d_in[24];
    const float* bn2_m   = (const float*)d_in[25];
    const float* bn2_v   = (const float*)d_in[26];

    float* ws = (float*)d_ws;
    float* h        = ws;                       // 8,388,608
    float* offx     = h + 8388608;              // 1,310,720
    float* offy     = offx + 1310720;           // 1,310,720
    float* cat      = offy + 1310720;           // 2,097,152
    float* stats_off= cat + 2097152;            // 40
    float* stats_cat= stats_off + 40;           // 16

    k_conv1<<<1024, 256, 0, stream>>>(x, conv1_w, bn1_g, bn1_b, bn1_m, bn1_v, h);
    k_offconv<<<256, 256, 0, stream>>>(h, offx_w, offy_w, offx_b, offy_b, offx, offy);
    k_offstats<<<20, 1024, 0, stream>>>(offx, offy, stats_off);
    k_dsc<<<dim3(128, 2), 256, 0, stream>>>(h, offx, offy, stats_off,
                                            gnoffx_g, gnoffx_b, gnoffy_g, gnoffy_b,
                                            dscx_w, dscy_w, dscx_b, dscy_b, cat);
    k_catstats<<<8, 1024, 0, stream>>>(cat, stats_cat);
    k_final<<<2048, 256, 0, stream>>>(cat, stats_cat, gnx_g, gnx_b, gny_g, gny_b,
                                      conv2_w, bn2_g, bn2_b, bn2_m, bn2_v,
                                      (float*)d_out);
}

// Round 5
// 369.681 us; speedup vs baseline: 2.1405x; 2.1405x over previous
//
#include <hip/hip_runtime.h>
#include <hip/hip_bf16.h>

// x: (2,3,512,512) fp32 -> conv1 s2 p1 -> h: chunked layout [b][4][256][256][16]
//   (64B per pixel-chunk => coalesced full-line reads for conv taps & gathers)
// off conv: 3x3 p1, 64->20 (both branches fused), raw outputs (2,65536,10)
// GN stats -> k_dsc applies GN+tanh inline, 2-pt lerp sample + K=5 conv -> cat (2,65536,16)
// final: GN + 1x1 conv 16->64 + BN + ReLU -> fp32 NCHW (2,64,256,256)

#define EPSF 1e-5f

typedef __attribute__((ext_vector_type(4))) float f4;

// h element index: ((b*4 + chunk)*65536 + i*256 + j)*16 + c   (c in 0..15)

// ---------------- Kernel 1: conv1 + bn1 + relu -> h chunked ------------------
__global__ __launch_bounds__(256) void k_conv1(
    const float* __restrict__ x, const float* __restrict__ w,
    const float* __restrict__ g, const float* __restrict__ bb,
    const float* __restrict__ m, const float* __restrict__ v,
    float* __restrict__ h)
{
    __shared__ float wl[27 * 64];            // [tap][oc]
    __shared__ float scale[64], shift[64];
    int t = threadIdx.x;
    for (int idx = t; idx < 1728; idx += 256) {
        int tap = idx >> 6, oc = idx & 63;
        wl[idx] = w[oc * 27 + tap];
    }
    if (t < 64) {
        float sc = g[t] * rsqrtf(v[t] + EPSF);
        scale[t] = sc; shift[t] = bb[t] - m[t] * sc;
    }
    __syncthreads();
    int lane = t & 63, wid = t >> 6;
    int blk = blockIdx.x;
    int b = blk >> 9;
    int rem = blk & 511;
    int i0 = (rem >> 2) * 2;
    int j0 = (rem & 3) * 64;
    int j = j0 + lane;
    f4 acc[2][4];
    #pragma unroll
    for (int r = 0; r < 2; ++r)
        #pragma unroll
        for (int q = 0; q < 4; ++q) acc[r][q] = (f4)0.f;
    #pragma unroll
    for (int ic = 0; ic < 3; ++ic) {
        #pragma unroll
        for (int dy = 0; dy < 3; ++dy) {
            const float* rowp[2]; bool vy[2];
            #pragma unroll
            for (int r = 0; r < 2; ++r) {
                int y = 2 * (i0 + r) + dy - 1;
                vy[r] = (unsigned)y < 512u;
                rowp[r] = x + ((size_t)(b * 3 + ic) * 512 + (vy[r] ? y : 0)) * 512;
            }
            #pragma unroll
            for (int dx = 0; dx < 3; ++dx) {
                int xx = 2 * j + dx - 1;
                bool vx = (unsigned)xx < 512u;
                int tap = ic * 9 + dy * 3 + dx;
                f4 w4[4];
                #pragma unroll
                for (int q = 0; q < 4; ++q)
                    w4[q] = *(const f4*)&wl[tap * 64 + wid * 16 + q * 4];
                #pragma unroll
                for (int r = 0; r < 2; ++r) {
                    float xv = (vy[r] && vx) ? rowp[r][xx] : 0.f;
                    #pragma unroll
                    for (int q = 0; q < 4; ++q) acc[r][q] += xv * w4[q];
                }
            }
        }
    }
    #pragma unroll
    for (int r = 0; r < 2; ++r) {
        size_t ij = (size_t)(i0 + r) * 256 + j;
        float* hp = h + ((size_t)(b * 4 + wid) * 65536 + ij) * 16;
        #pragma unroll
        for (int q = 0; q < 4; ++q) {
            f4 sc = *(const f4*)&scale[wid * 16 + q * 4];
            f4 sh = *(const f4*)&shift[wid * 16 + q * 4];
            f4 val = acc[r][q] * sc + sh;
            f4 rv;
            #pragma unroll
            for (int e = 0; e < 4; ++e) rv[e] = fmaxf(val[e], 0.f);
            *(f4*)(hp + q * 4) = rv;
        }
    }
}

// ---------------- Kernel 2: both offset convs (3x3 p1, 64 -> 20) -------------
// block = 256; tile 64 j (lanes) x 8 i (4 waves x 2 rows/thread). grid = 256.
// Streaming structure: unroll 1 on chunk/ky/kx to keep VGPR < 128 (R4 spill fix).
__global__ __launch_bounds__(256) void k_offconv(
    const float* __restrict__ h,
    const float* __restrict__ wx, const float* __restrict__ wy,
    const float* __restrict__ bx, const float* __restrict__ by,
    float* __restrict__ offx, float* __restrict__ offy)
{
    __shared__ float wl[9 * 64 * 20];        // [tap][c][o20], 80B rows
    __shared__ float bias[20];
    int t = threadIdx.x;
    for (int idx = t; idx < 11520; idx += 256) {
        int o = idx % 20;
        int rest = idx / 20;                 // tap*64 + c
        int c = rest & 63, tap = rest >> 6;
        wl[idx] = (o < 10) ? wx[((size_t)o * 64 + c) * 9 + tap]
                           : wy[((size_t)(o - 10) * 64 + c) * 9 + tap];
    }
    if (t < 20) bias[t] = (t < 10) ? bx[t] : by[t - 10];
    __syncthreads();
    int lane = t & 63, wid = t >> 6;
    int blk = blockIdx.x;
    int b = blk >> 7;
    int rem = blk & 127;
    int i0 = (rem >> 2) * 8 + wid * 2;
    int j0 = (rem & 3) * 64;
    int j = j0 + lane;
    f4 acc[2][5];
    #pragma unroll
    for (int r = 0; r < 2; ++r)
        #pragma unroll
        for (int q = 0; q < 5; ++q) acc[r][q] = (f4)0.f;
    #pragma unroll 1
    for (int chunk = 0; chunk < 4; ++chunk) {
        const float* hc = h + ((size_t)(b * 4 + chunk) * 65536) * 16;
        #pragma unroll 1
        for (int ky = 0; ky < 3; ++ky) {
            int y0 = i0 + ky - 1;
            int y1 = y0 + 1;
            bool vy0 = (unsigned)y0 < 256u;
            bool vy1 = (unsigned)y1 < 256u;
            const float* rp0 = hc + (size_t)(vy0 ? y0 : 0) * 256 * 16;
            const float* rp1 = hc + (size_t)(vy1 ? y1 : 0) * 256 * 16;
            #pragma unroll 1
            for (int kx = 0; kx < 3; ++kx) {
                int xx = j + kx - 1;
                bool vx = (unsigned)xx < 256u;
                size_t colofs = (size_t)(vx ? xx : 0) * 16;
                const float* wt = &wl[((ky * 3 + kx) * 64 + chunk * 16) * 20];
                #pragma unroll 2
                for (int cq = 0; cq < 4; ++cq) {
                    f4 h0 = (vy0 && vx) ? *(const f4*)(rp0 + colofs + cq * 4) : (f4)0.f;
                    f4 h1 = (vy1 && vx) ? *(const f4*)(rp1 + colofs + cq * 4) : (f4)0.f;
                    #pragma unroll
                    for (int ci = 0; ci < 4; ++ci) {
                        const float* wr = &wt[(cq * 4 + ci) * 20];
                        f4 w0 = *(const f4*)&wr[0];
                        f4 w1 = *(const f4*)&wr[4];
                        f4 w2 = *(const f4*)&wr[8];
                        f4 w3 = *(const f4*)&wr[12];
                        f4 w4v = *(const f4*)&wr[16];
                        float a0 = h0[ci], a1 = h1[ci];
                        acc[0][0] += a0 * w0;
                        acc[0][1] += a0 * w1;
                        acc[0][2] += a0 * w2;
                        acc[0][3] += a0 * w3;
                        acc[0][4] += a0 * w4v;
                        acc[1][0] += a1 * w0;
                        acc[1][1] += a1 * w1;
                        acc[1][2] += a1 * w2;
                        acc[1][3] += a1 * w3;
                        acc[1][4] += a1 * w4v;
                    }
                }
            }
        }
    }
    #pragma unroll
    for (int r = 0; r < 2; ++r) {
        size_t p = (size_t)b * 65536 + (size_t)(i0 + r) * 256 + j;
        float* ox = offx + p * 10;
        float* oy = offy + p * 10;
        #pragma unroll
        for (int q = 0; q < 5; ++q)
            #pragma unroll
            for (int e = 0; e < 4; ++e) {
                int o = q * 4 + e;
                float val = acc[r][q][e] + bias[o];
                if (o < 10) ox[o] = val; else oy[o - 10] = val;
            }
    }
}

// ---------------- block reduce helper ----------------------------------------
__device__ __forceinline__ void block_reduce2(float& s, float& s2, float* lds) {
    #pragma unroll
    for (int o = 32; o >= 1; o >>= 1) {
        s  += __shfl_xor(s,  o, 64);
        s2 += __shfl_xor(s2, o, 64);
    }
    int wv = threadIdx.x >> 6, lane = threadIdx.x & 63;
    if (lane == 0) { lds[wv * 2] = s; lds[wv * 2 + 1] = s2; }
    __syncthreads();
    if (threadIdx.x == 0) {
        int nw = blockDim.x >> 6;
        float a = 0.f, b2 = 0.f;
        for (int k = 0; k < nw; ++k) { a += lds[k * 2]; b2 += lds[k * 2 + 1]; }
        s = a; s2 = b2;
    }
}

// ---------------- Kernel 3: offset GN stats ----------------------------------
__global__ __launch_bounds__(1024) void k_offstats(
    const float* __restrict__ offx,
    const float* __restrict__ offy,
    float* __restrict__ stats)               // 20 * {mean, rstd}
{
    __shared__ float lds[32];
    int gid = blockIdx.x;                    // branch*10 + b*5 + g
    int branch = gid / 10;
    int b = (gid / 5) % 2;
    int g = gid % 5;
    const float* arr = branch ? offy : offx;
    int t = threadIdx.x;
    float s = 0.f, s2 = 0.f;
    for (int pix = t; pix < 65536; pix += 1024) {
        const float* pp = &arr[((size_t)b * 65536 + pix) * 10 + g * 2];
        float a = pp[0], c = pp[1];
        s += a + c; s2 += a * a + c * c;
    }
    block_reduce2(s, s2, lds);
    if (t == 0) {
        float n = 131072.f;
        float mean = s / n;
        float var = s2 / n - mean * mean;
        stats[gid * 2] = mean;
        stats[gid * 2 + 1] = rsqrtf(var + EPSF);
    }
}

// ---------------- Kernel 4: GN+tanh (inline) + 2pt-lerp + deform conv ---------
// block = 256; tile 64 j (lanes) x 16 i (4 waves x 4 rows/thread). grid (128,2).
__global__ __launch_bounds__(256) void k_dsc(
    const float* __restrict__ h,
    const float* __restrict__ offx, const float* __restrict__ offy,
    const float* __restrict__ stats,
    const float* __restrict__ gx, const float* __restrict__ bxg,
    const float* __restrict__ gy, const float* __restrict__ byg,
    const float* __restrict__ wx_,  // dscx_w (8,64,5)
    const float* __restrict__ wy_,  // dscy_w (8,64,5)
    const float* __restrict__ bx_, const float* __restrict__ by_,
    float* __restrict__ cat)        // (2,65536,16)
{
    int branch = blockIdx.y;
    __shared__ float wl[2560];               // [k][c][oc8], 32B rows
    __shared__ float bias[8];
    const float* wsrc = branch ? wy_ : wx_;
    int t = threadIdx.x;
    for (int idx = t; idx < 2560; idx += 256) {
        int oc = idx & 7;
        int rest = idx >> 3;                 // k*64 + c
        int c = rest & 63, k = rest >> 6;
        wl[idx] = wsrc[(size_t)oc * 320 + c * 5 + k];
    }
    if (t < 8) bias[t] = (branch ? by_ : bx_)[t];
    __syncthreads();
    int lane = t & 63, wid = t >> 6;
    int blk = blockIdx.x;
    int b = blk >> 6;
    int rem = blk & 63;
    int i0 = (rem >> 2) * 16 + wid * 4;
    int j0 = (rem & 3) * 64;
    int j = j0 + lane;
    const float* offarr = branch ? offy : offx;
    const float* goff = branch ? gy : gx;
    const float* boff = branch ? byg : bxg;
    int cbase = branch * 5;
    float cum[4][5];
    #pragma unroll
    for (int r = 0; r < 4; ++r) {
        size_t p = (size_t)b * 65536 + (size_t)(i0 + r) * 256 + j;
        const float* op = offarr + p * 10 + cbase;
        float tv[4];
        const int idxs[4] = {0, 1, 3, 4};
        #pragma unroll
        for (int u = 0; u < 4; ++u) {
            int c = cbase + idxs[u];
            int g = c >> 1;
            int sidx = branch * 10 + b * 5 + g;
            float mean = stats[sidx * 2], rstd = stats[sidx * 2 + 1];
            float val = (op[idxs[u]] - mean) * rstd * goff[c] + boff[c];
            tv[u] = tanhf(val);
        }
        cum[r][0] = tv[0] + tv[1]; cum[r][1] = tv[1]; cum[r][2] = 0.f;
        cum[r][3] = tv[2]; cum[r][4] = tv[2] + tv[3];
    }
    f4 acc[4][2];
    #pragma unroll
    for (int r = 0; r < 4; ++r) { acc[r][0] = (f4)0.f; acc[r][1] = (f4)0.f; }
    #pragma unroll
    for (int k = 0; k < 5; ++k) {
        int pixA[4], pixB[4]; float fr[4];
        #pragma unroll
        for (int r = 0; r < 4; ++r) {
            int i = i0 + r;
            if (branch == 0) {
                float yf = (float)i + cum[r][k];
                yf = fminf(fmaxf(yf, 0.f), 255.f);
                float y0 = floorf(yf);
                fr[r] = yf - y0;
                int y0i = (int)y0;
                int y1i = min(y0i + 1, 255);
                int xi = min(max(j + k - 2, 0), 255);
                pixA[r] = y0i * 256 + xi;
                pixB[r] = y1i * 256 + xi;
            } else {
                float xf = (float)j + cum[r][k];
                xf = fminf(fmaxf(xf, 0.f), 255.f);
                float x0 = floorf(xf);
                fr[r] = xf - x0;
                int x0i = (int)x0;
                int x1i = min(x0i + 1, 255);
                int yi = min(max(i + k - 2, 0), 255);
                pixA[r] = yi * 256 + x0i;
                pixB[r] = yi * 256 + x1i;
            }
        }
        #pragma unroll 1
        for (int chunk = 0; chunk < 4; ++chunk) {
            const float* hc = h + ((size_t)(b * 4 + chunk) * 65536) * 16;
            const float* wk = &wl[((size_t)k * 64 + chunk * 16) * 8];
            #pragma unroll
            for (int cq = 0; cq < 4; ++cq) {
                f4 vv[4];
                #pragma unroll
                for (int r = 0; r < 4; ++r) {
                    f4 va = *(const f4*)(hc + (size_t)pixA[r] * 16 + cq * 4);
                    f4 vb = *(const f4*)(hc + (size_t)pixB[r] * 16 + cq * 4);
                    vv[r] = va + fr[r] * (vb - va);
                }
                #pragma unroll
                for (int ci = 0; ci < 4; ++ci) {
                    f4 w0 = *(const f4*)&wk[(cq * 4 + ci) * 8];
                    f4 w1 = *(const f4*)&wk[(cq * 4 + ci) * 8 + 4];
                    #pragma unroll
                    for (int r = 0; r < 4; ++r) {
                        acc[r][0] += vv[r][ci] * w0;
                        acc[r][1] += vv[r][ci] * w1;
                    }
                }
            }
        }
    }
    #pragma unroll
    for (int r = 0; r < 4; ++r) {
        size_t p = (size_t)b * 65536 + (size_t)(i0 + r) * 256 + j;
        f4 v0 = acc[r][0] + *(const f4*)&bias[0];
        f4 v1 = acc[r][1] + *(const f4*)&bias[4];
        *(f4*)&cat[p * 16 + branch * 8] = v0;
        *(f4*)&cat[p * 16 + branch * 8 + 4] = v1;
    }
}

// ---------------- Kernel 5: cat GN stats (8 groups of 4ch x 65536) ------------
__global__ __launch_bounds__(1024) void k_catstats(
    const float* __restrict__ cat, float* __restrict__ stats)
{
    __shared__ float lds[32];
    int gid = blockIdx.x;                    // b*4 + branch*2 + g
    int b = gid >> 2;
    int cbase = ((gid >> 1) & 1) * 8 + (gid & 1) * 4;
    int t = threadIdx.x;
    float s = 0.f, s2 = 0.f;
    for (int pix = t; pix < 65536; pix += 1024) {
        const float* pp = &cat[((size_t)b * 65536 + pix) * 16 + cbase];
        #pragma unroll
        for (int c = 0; c < 4; ++c) { float a = pp[c]; s += a; s2 += a * a; }
    }
    block_reduce2(s, s2, lds);
    if (t == 0) {
        float n = 262144.f;
        float mean = s / n;
        float var = s2 / n - mean * mean;
        stats[gid * 2] = mean;
        stats[gid * 2 + 1] = rsqrtf(var + EPSF);
    }
}

// ---------------- Kernel 6: GN+relu + 1x1 conv + bn2 + relu -> fp32 out -------
__global__ __launch_bounds__(256) void k_final(
    const float* __restrict__ cat,
    const float* __restrict__ stats,
    const float* __restrict__ gnx_g, const float* __restrict__ gnx_b,
    const float* __restrict__ gny_g, const float* __restrict__ gny_b,
    const float* __restrict__ w2,    // (64,16)
    const float* __restrict__ g2, const float* __restrict__ b2,
    const float* __restrict__ m2, const float* __restrict__ v2,
    float* __restrict__ out)         // (2,64,256,256)
{
    __shared__ float wl[1024];
    __shared__ float sc2[64], sh2[64];
    __shared__ float cmean[16], crstd[16], cg[16], cb[16];
    int t = threadIdx.x;
    int pbase = blockIdx.x * 64;
    int b = pbase >> 16;
    for (int idx = t; idx < 1024; idx += 256) wl[idx] = w2[idx];
    if (t < 64) {
        float sc = g2[t] * rsqrtf(v2[t] + EPSF);
        sc2[t] = sc;
        sh2[t] = b2[t] - m2[t] * sc;
    }
    if (t < 16) {
        int branch = t >> 3; int cc = t & 7; int g = cc >> 2;
        int sidx = b * 4 + branch * 2 + g;
        cmean[t] = stats[sidx * 2];
        crstd[t] = stats[sidx * 2 + 1];
        cg[t] = branch ? gny_g[cc] : gnx_g[cc];
        cb[t] = branch ? gny_b[cc] : gnx_b[cc];
    }
    __syncthreads();
    int lane = t & 63, wq = t >> 6;
    int p = pbase + lane;
    int ij = p & 65535;
    float vv[16];
    const float* cp = &cat[(size_t)p * 16];
    #pragma unroll
    for (int c = 0; c < 16; ++c) {
        float x = (cp[c] - cmean[c]) * crstd[c] * cg[c] + cb[c];
        vv[c] = fmaxf(x, 0.f);
    }
    #pragma unroll
    for (int q = 0; q < 16; ++q) {
        int oc = wq + q * 4;
        float s = 0.f;
        #pragma unroll
        for (int c = 0; c < 16; ++c) s += vv[c] * wl[oc * 16 + c];
        float r = fmaxf(s * sc2[oc] + sh2[oc], 0.f);
        out[((size_t)(b * 64 + oc) << 16) + ij] = r;
    }
}

extern "C" void kernel_launch(void* const* d_in, const int* in_sizes, int n_in,
                              void* d_out, int out_size, void* d_ws, size_t ws_size,
                              hipStream_t stream) {
    const float* x       = (const float*)d_in[0];
    const float* conv1_w = (const float*)d_in[1];
    const float* bn1_g   = (const float*)d_in[2];
    const float* bn1_b   = (const float*)d_in[3];
    const float* bn1_m   = (const float*)d_in[4];
    const float* bn1_v   = (const float*)d_in[5];
    const float* offx_w  = (const float*)d_in[6];
    const float* offx_b  = (const float*)d_in[7];
    const float* gnoffx_g= (const float*)d_in[8];
    const float* gnoffx_b= (const float*)d_in[9];
    const float* dscx_w  = (const float*)d_in[10];
    const float* dscx_b  = (const float*)d_in[11];
    const float* gnx_g   = (const float*)d_in[12];
    const float* gnx_b   = (const float*)d_in[13];
    const float* offy_w  = (const float*)d_in[14];
    const float* offy_b  = (const float*)d_in[15];
    const float* gnoffy_g= (const float*)d_in[16];
    const float* gnoffy_b= (const float*)d_in[17];
    const float* dscy_w  = (const float*)d_in[18];
    const float* dscy_b  = (const float*)d_in[19];
    const float* gny_g   = (const float*)d_in[20];
    const float* gny_b   = (const float*)d_in[21];
    const float* conv2_w = (const float*)d_in[22];
    const float* bn2_g   = (const float*)d_in[23];
    const float* bn2_b   = (const float*)d_in[24];
    const float* bn2_m   = (const float*)d_in[25];
    const float* bn2_v   = (const float*)d_in[26];

    float* ws = (float*)d_ws;
    float* h        = ws;                       // 8,388,608
    float* offx     = h + 8388608;              // 1,310,720
    float* offy     = offx + 1310720;           // 1,310,720
    float* cat      = offy + 1310720;           // 2,097,152
    float* stats_off= cat + 2097152;            // 40
    float* stats_cat= stats_off + 40;           // 16

    k_conv1<<<1024, 256, 0, stream>>>(x, conv1_w, bn1_g, bn1_b, bn1_m, bn1_v, h);
    k_offconv<<<256, 256, 0, stream>>>(h, offx_w, offy_w, offx_b, offy_b, offx, offy);
    k_offstats<<<20, 1024, 0, stream>>>(offx, offy, stats_off);
    k_dsc<<<dim3(128, 2), 256, 0, stream>>>(h, offx, offy, stats_off,
                                            gnoffx_g, gnoffx_b, gnoffy_g, gnoffy_b,
                                            dscx_w, dscy_w, dscx_b, dscy_b, cat);
    k_catstats<<<8, 1024, 0, stream>>>(cat, stats_cat);
    k_final<<<2048, 256, 0, stream>>>(cat, stats_cat, gnx_g, gnx_b, gny_g, gny_b,
                                      conv2_w, bn2_g, bn2_b, bn2_m, bn2_v,
                                      (float*)d_out);
}